// Round 13
// baseline (272.680 us; speedup 1.0000x reference)
//
#include <hip/hip_runtime.h>
#include <stdint.h>

#define HW    50176   // 224*224
#define BATCH 16
#define NSEG  196
#define EMB   16
#define MC    16
#define JITTER 0.001f
#define EBLK  14      // emb blocks per batch
#define PXB   3584    // pixels per emb block (50176/14)

// ---------------- threefry2x32 (20 rounds), bit-exact vs JAX ----------------
__host__ __device__ inline void threefry2x32(uint32_t k0, uint32_t k1,
                                             uint32_t x0, uint32_t x1,
                                             uint32_t& o0, uint32_t& o1) {
  uint32_t k2 = k0 ^ k1 ^ 0x1BD11BDAu;
#define TFR(r) { x0 += x1; x1 = (x1 << (r)) | (x1 >> (32 - (r))); x1 ^= x0; }
  x0 += k0; x1 += k1;
  TFR(13) TFR(15) TFR(26) TFR(6)
  x0 += k1; x1 += k2 + 1u;
  TFR(17) TFR(29) TFR(16) TFR(24)
  x0 += k2; x1 += k0 + 2u;
  TFR(13) TFR(15) TFR(26) TFR(6)
  x0 += k0; x1 += k1 + 3u;
  TFR(17) TFR(29) TFR(16) TFR(24)
  x0 += k1; x1 += k2 + 4u;
  TFR(13) TFR(15) TFR(26) TFR(6)
  x0 += k2; x1 += k0 + 5u;
#undef TFR
  o0 = x0; o1 = x1;
}

// XLA ErfInv (f32), Giles polynomial
__device__ inline float erfinv_f32(float x) {
  float w = -log1pf(-x * x);
  float p;
  if (w < 5.0f) {
    w = w - 2.5f;
    p = 2.81022636e-08f;
    p = 3.43273939e-07f + p * w;
    p = -3.5233877e-06f + p * w;
    p = -4.39150654e-06f + p * w;
    p = 0.00021858087f + p * w;
    p = -0.00125372503f + p * w;
    p = -0.00417768164f + p * w;
    p = 0.246640727f + p * w;
    p = 1.50140941f + p * w;
  } else {
    w = sqrtf(w) - 3.0f;
    p = -0.000200214257f;
    p = 0.000100950558f + p * w;
    p = 0.00134934322f + p * w;
    p = -0.00367342844f + p * w;
    p = 0.00573950773f + p * w;
    p = -0.0076224613f + p * w;
    p = 0.00943887047f + p * w;
    p = 1.00167406f + p * w;
    p = 2.83297682f + p * w;
  }
  return p * x;
}

__device__ inline float bits_to_f01(uint32_t bits) {
  uint32_t fb = (bits >> 9) | 0x3F800000u;
  return __uint_as_float(fb) - 1.0f;
}

// ---------------- K1: pixel_probs + per-block segment sums of x,cnt --------
// Linearity: sum_emb_j[g] = W[j,:].sum_x[g] + b_j*cnt[g]; accumulate only
// 3 input channels + count.  partial: [b*EBLK+bb][4][196] (c-major).
__global__ __launch_bounds__(256) void emb_kernel(
    const float* __restrict__ x, const int* __restrict__ groups,
    const float* __restrict__ Wc, const float* __restrict__ bc,
    float* __restrict__ partial, float* __restrict__ pixel_probs) {
  __shared__ float lsum[4 * NSEG];  // [c][g]
  int b = blockIdx.x / EBLK;
  int blk = blockIdx.x % EBLK;
  int tid = threadIdx.x;
  for (int i = tid; i < 4 * NSEG; i += 256) lsum[i] = 0.0f;
  __syncthreads();
  const float* xb = x + (size_t)b * 3 * HW;
  float w0 = Wc[0], w1 = Wc[1], w2 = Wc[2], b0 = bc[0];
  for (int k = 0; k < PXB / 256; ++k) {
    int p = blk * PXB + k * 256 + tid;
    float x0 = xb[p], x1 = xb[HW + p], x2 = xb[2 * HW + p];
    int g = groups[b * HW + p];
    float e = w0 * x0 + w1 * x1;
    e = e + w2 * x2 + b0;
    pixel_probs[b * HW + p] = 1.0f / (1.0f + expf(-e));
    atomicAdd(&lsum[g], x0);
    atomicAdd(&lsum[NSEG + g], x1);
    atomicAdd(&lsum[2 * NSEG + g], x2);
    atomicAdd(&lsum[3 * NSEG + g], 1.0f);
  }
  __syncthreads();
  float* pb = partial + (size_t)blockIdx.x * (4 * NSEG);
  if (tid < NSEG) {
#pragma unroll
    for (int c = 0; c < 4; ++c) pb[c * NSEG + tid] = lsum[c * NSEG + tid];
  }
}

// ---------------- K2: FUSED stats + sigma + rng + Cholesky + hard ----------
// One block per batch.  Values are bit-identical to the round-12 chain:
// stats sums (same bb/j order), sigma fma order (j ascending, ge[j][s]
// broadcast x gt register), and the R12 row-split Schur recurrence with
// double-buffered LDS pivot + per-step barrier.  Only storage changed:
// G and mu stay in LDS instead of a global round-trip (Gc/mu_ws deleted),
// and 2 kernel launches are removed.
__global__ __launch_bounds__(256, 1) void fused_kernel(
    const float* __restrict__ partial, const float* __restrict__ Wc,
    const float* __restrict__ bc,
    uint32_t kg0, uint32_t kg1, uint32_t ku0, uint32_t ku1,
    float* __restrict__ group_probs, float* __restrict__ sigma_out,
    float* __restrict__ hard) {
  int b = blockIdx.x;
  int tid = threadIdx.x;
  int lane = tid & 63;
  int wave = tid >> 6;
  __shared__ float ge[15][NSEG];                // 11.76 KB
  __shared__ float mu_l[NSEG];
  __shared__ float eps_lds[NSEG * MC];          // 12.25 KB
  __shared__ __align__(16) float piv[2][16];    // double-buffered pivot row

  // eps = sqrt(2)*erfinv(bits) straight into LDS
  for (int t = tid; t < NSEG * MC; t += 256) {
    uint32_t a0, a1;
    threefry2x32(kg0, kg1, 0u, (uint32_t)(b * NSEG * MC + t), a0, a1);
    float f = bits_to_f01(a0 ^ a1);
    const float lo = -0.99999994f;  // nextafter(-1,0)
    float u = fmaxf(lo, f * (1.0f - lo) + lo);
    eps_lds[t] = 1.4142135623730951f * erfinv_f32(u);
  }

  // stats (identical op order to R12 stats_kernel)
  if (tid < NSEG) {
    float sx0 = 0.0f, sx1 = 0.0f, sx2 = 0.0f, cn = 0.0f;
    for (int bb = 0; bb < EBLK; ++bb) {
      const float* pb = partial + (size_t)(b * EBLK + bb) * (4 * NSEG);
      sx0 += pb[tid]; sx1 += pb[NSEG + tid];
      sx2 += pb[2 * NSEG + tid]; cn += pb[3 * NSEG + tid];
    }
    float denom = fmaxf(cn, 1.0f);
#pragma unroll
    for (int j = 0; j < EMB; ++j) {
      float e = Wc[j * 3 + 0] * sx0 + Wc[j * 3 + 1] * sx1;
      e = e + Wc[j * 3 + 2] * sx2 + bc[j] * cn;
      float v = e / denom;
      if (j == 0) {
        mu_l[tid] = v;
        group_probs[b * NSEG + tid] = 1.0f / (1.0f + expf(-v));
      } else {
        ge[j - 1][tid] = v;
      }
    }
  }
  __syncthreads();  // ge, mu_l, eps_lds visible

  // sigma = G G^T + jitter*I (same fma order as R12 sigma_kernel)
  if (tid < NSEG) {
    int t = tid;
    float gt[15];
#pragma unroll
    for (int j = 0; j < 15; ++j) gt[j] = ge[j][t];
    for (int s = 0; s < NSEG; ++s) {
      float a = 0.0f;
#pragma unroll
      for (int j = 0; j < 15; ++j) a = fmaf(ge[j][s], gt[j], a);  // broadcast
      if (s == t) a += JITTER;
      sigma_out[((size_t)b * NSEG + s) * NSEG + t] = a;
    }
  }

  // row-split Cholesky + L@eps (R12, bit-identical); g from LDS ge
  int i = tid;  // wave*64+lane
  float g[15];
#pragma unroll
  for (int j = 0; j < 15; ++j) g[j] = (i < NSEG) ? ge[j][i] : 0.0f;
  float acc[16];
#pragma unroll
  for (int m = 0; m < 16; ++m) acc[m] = 0.0f;
  if (tid == 0) {
#pragma unroll
    for (int j = 0; j < 15; ++j) piv[0][j] = g[j];
    piv[0][15] = 0.0f;
  }
  __syncthreads();

  const float sj = 0.031622776601683794f;  // sqrt(jitter)
  for (int k = 0; k < NSEG; ++k) {
    const float* pv = piv[k & 1];
    float4 p0 = *(const float4*)(pv);
    float4 p1 = *(const float4*)(pv + 4);
    float4 p2 = *(const float4*)(pv + 8);
    float4 p3 = *(const float4*)(pv + 12);
    float gk[15] = {p0.x, p0.y, p0.z, p0.w, p1.x, p1.y, p1.z, p1.w,
                    p2.x, p2.y, p2.z, p2.w, p3.x, p3.y, p3.z};
    // R11/R12 tree norm + rsq/rcp (passing numerics, unchanged)
    float t0 = fmaf(gk[0], gk[0], JITTER);
    float t1 = gk[1] * gk[1];   float t2 = gk[2] * gk[2];
    float t3 = gk[3] * gk[3];   float t4 = gk[4] * gk[4];
    float t5 = gk[5] * gk[5];   float t6 = gk[6] * gk[6];
    float t7 = gk[7] * gk[7];   float t8 = gk[8] * gk[8];
    float t9 = gk[9] * gk[9];   float t10 = gk[10] * gk[10];
    float t11 = gk[11] * gk[11]; float t12 = gk[12] * gk[12];
    float t13 = gk[13] * gk[13]; float t14 = gk[14] * gk[14];
    float u0 = t0 + t1, u1 = t2 + t3, u2 = t4 + t5, u3 = t6 + t7;
    float u4 = t8 + t9, u5 = t10 + t11, u6 = t12 + t13;
    float v0 = u0 + u1, v1 = u2 + u3, v2 = u4 + u5, v3 = u6 + t14;
    float jn = (v0 + v1) + (v2 + v3);
    float invd = __builtin_amdgcn_rsqf(jn);
    float dd = jn * invd;
    float beta = (invd * invd) * __builtin_amdgcn_rcpf(fmaf(sj, invd, 1.0f));

    int s0 = k >> 6;
    if (wave >= s0) {  // retired waves just hit the barrier
      const float4* ep = (const float4*)(eps_lds + k * MC);
      float4 e0 = ep[0], e1 = ep[1], e2 = ep[2], e3 = ep[3];
      float ek[16] = {e0.x, e0.y, e0.z, e0.w, e1.x, e1.y, e1.z, e1.w,
                      e2.x, e2.y, e2.z, e2.w, e3.x, e3.y, e3.z, e3.w};
      float dot = 0.0f;
#pragma unroll
      for (int j = 0; j < 15; ++j) dot = fmaf(g[j], gk[j], dot);
      float w;
      if (wave == s0) {
        int owner = k & 63;
        w = (lane > owner) ? dot * invd : ((lane == owner) ? dd : 0.0f);
      } else {
        w = dot * invd;  // i > k always; dead rows (g==+0) give w=+0
      }
#pragma unroll
      for (int m = 0; m < 16; ++m) acc[m] = fmaf(w, ek[m], acc[m]);
      float bd = beta * dot;
#pragma unroll
      for (int j = 0; j < 15; ++j) g[j] = fmaf(-bd, gk[j], g[j]);
      int kn = k + 1;
      if (kn < NSEG && i == kn) {  // single owner lane publishes row k+1
        float* pw = piv[kn & 1];
#pragma unroll
        for (int j = 0; j < 15; ++j) pw[j] = g[j];
      }
    }
    __syncthreads();  // fences publish before next step's read
  }

  // epilogue: hard = (mu + L@eps + logistic) > 0
  if (i < NSEG) {
    float mui = mu_l[i];
    float4 outv[4];
    float* op = (float*)outv;
#pragma unroll
    for (int m = 0; m < 16; ++m) {
      uint32_t a0, a1;
      threefry2x32(ku0, ku1, 0u, (uint32_t)(b * NSEG * MC + i * MC + m), a0, a1);
      float f = bits_to_f01(a0 ^ a1);
      const float mn = 1e-6f;
      const float mx = (float)(1.0 - 1e-6);
      float uu = fmaxf(mn, f * (mx - mn) + mn);
      float lg = logf(uu) - log1pf(-uu);
      float z = mui + acc[m] + lg;
      op[m] = (z > 0.0f) ? 1.0f : 0.0f;
    }
    float4* hp = (float4*)(hard + ((size_t)b * NSEG + i) * MC);
#pragma unroll
    for (int q = 0; q < 4; ++q) hp[q] = outv[q];
  }
}

// ---------------- K3: mask gather, one float4 per thread -------------------
__global__ __launch_bounds__(256) void mask_kernel(
    const int* __restrict__ groups, const float* __restrict__ hard,
    float4* __restrict__ out) {
  int f = blockIdx.x * blockDim.x + threadIdx.x;  // float4 index
  if (f >= BATCH * 3 * HW * 4) return;
  int pix = f >> 2;          // (b*3+c)*HW + p
  int q = f & 3;
  int b = pix / (3 * HW);
  int p = pix % HW;
  int g = groups[b * HW + p];
  out[f] = ((const float4*)hard)[(b * NSEG + g) * 4 + q];
}

extern "C" void kernel_launch(void* const* d_in, const int* in_sizes, int n_in,
                              void* d_out, int out_size, void* d_ws, size_t ws_size,
                              hipStream_t stream) {
  const float* x = (const float*)d_in[0];
  const int* groups = (const int*)d_in[1];
  const float* Wc = (const float*)d_in[2];
  const float* bc = (const float*)d_in[3];

  float* out = (float*)d_out;
  float* mask_out = out;                         // 38,535,168
  float* gp_out = out + 38535168;                //      3,136
  float* pp_out = gp_out + 3136;                 //    802,816
  float* sig_out = pp_out + 802816;              //    614,656

  float* ws = (float*)d_ws;
  float* partial = ws;                           // 224*784 = 175,616
  float* hard    = ws + 175616;                  //  50,176 — own region:
                                                 // fused kernel reads partial
                                                 // and writes hard concurrently
                                                 // across blocks (no aliasing)

  emb_kernel<<<BATCH * EBLK, 256, 0, stream>>>(x, groups, Wc, bc, partial, pp_out);

  uint32_t kg0, kg1, ku0, ku1;
  threefry2x32(0u, 42u, 0u, 0u, kg0, kg1);
  threefry2x32(0u, 42u, 0u, 1u, ku0, ku1);

  fused_kernel<<<BATCH, 256, 0, stream>>>(partial, Wc, bc, kg0, kg1, ku0, ku1,
                                          gp_out, sig_out, hard);
  mask_kernel<<<(BATCH * 3 * HW * 4 + 255) / 256, 256, 0, stream>>>(
      groups, hard, (float4*)mask_out);
}